// Round 16
// baseline (99.121 us; speedup 1.0000x reference)
//
#include <hip/hip_runtime.h>
#include <math.h>

#define TT 128
#define IN_CH 32
#define NPATH 256
#define SIGCH 7380
#define K1 29520
#define N1 512
#define N2 256
#define BKG 8

// ---------------- Kernel 1: conv + time-augment + depth-4 signature ----------------
// 512-thread block per path, 2 groups of 243 threads, Chen 2-way time-split.
// ONLY change vs r15: __launch_bounds__(512,1) — the (512,2) variant capped
// VGPR at 128 while the scan needs ~130-150 live (A4[9] f4 = 36 + S4 27 + ...)
// -> suspected scratch spills in the hot loop. If this was the sig wall, it
// drops to ~15us; if not, sig now surfaces in the top-5 with counters.
__global__ __launch_bounds__(512, 1) void sig_kernel(const float* __restrict__ x,
        const float* __restrict__ cw, const float* __restrict__ cb,
        float* __restrict__ sig /*[256][7380]*/) {
    __shared__ float incT[9][132];
    __shared__ __align__(16) float sb1[12];
    __shared__ __align__(16) float sb2[9][12];
    __shared__ __align__(16) float sb3[81][12];
    __shared__ __align__(16) float sb4[729][12];
    const int p = blockIdx.x;
    const int b = p >> 2, oc = p & 3;
    const int tid = threadIdx.x;

    const float4 wv = *(const float4*)(cw + oc * 4);
    const float bias = cb[oc];
    const float* xb = x + (long)b * TT * IN_CH;

    for (int it = tid; it < TT * 8; it += 512) {
        const int t = it >> 3, ch = it & 7;
        const float4 xa = *(const float4*)(xb + t * IN_CH + ch * 4);
        float v = xa.x * wv.x + xa.y * wv.y + xa.z * wv.z + xa.w * wv.w + bias;
        if (t > 0) {
            const float4 xm = *(const float4*)(xb + (t - 1) * IN_CH + ch * 4);
            v -= xm.x * wv.x + xm.y * wv.y + xm.z * wv.z + xm.w * wv.w + bias;
        }
        incT[1 + ch][t] = v;
    }
    if (tid < TT) incT[0][tid] = tid ? (1.f / 127.f) : 0.f;
    __syncthreads();

    const int g = tid >> 8;
    const int gtid = tid & 255;
    const bool act = gtid < 243;
    const int base3 = 3 * gtid;
    const int i1 = base3 / 81;
    const int i2 = (base3 / 9) % 9;
    const int i30 = base3 % 9;

    float S4[3][9] = {};
    float s3[3] = {0.f, 0.f, 0.f};
    float s2 = 0.f, s1 = 0.f;

#define LD(R, T4) (*(const float4*)&incT[(R)][(T4)])
#define STEP4(CMP) do { \
    const float E1 = e1v.CMP, E2 = e2v.CMP; \
    const float F0 = f0v.CMP, F1 = f1v.CMP, F2 = f2v.CMP; \
    const float t12 = E1 * E2; \
    const float s1d2 = s1 * E2; \
    const float Ak = t12 * (1.f / 24.f) + s1d2 * (1.f / 6.f) + s2 * 0.5f; \
    const float Bk = t12 * (1.f / 6.f) + s1d2 * 0.5f + s2; \
    const float K0 = F0 * Ak + s3[0]; \
    const float K1v = F1 * Ak + s3[1]; \
    const float K2v = F2 * Ak + s3[2]; \
    _Pragma("unroll") \
    for (int c = 0; c < 9; ++c) { \
        const float Ac = A4[c].CMP; \
        S4[0][c] += K0 * Ac; S4[1][c] += K1v * Ac; S4[2][c] += K2v * Ac; \
    } \
    s3[0] += Bk * F0; s3[1] += Bk * F1; s3[2] += Bk * F2; \
    s2 += E2 * (0.5f * E1 + s1); \
    s1 += E1; \
} while (0)

    if (act) {
        const int t0g = g * 64;
        for (int gg = 0; gg < 16; ++gg) {
            const int t4 = t0g + gg * 4;
            float4 A4[9];
#pragma unroll
            for (int c = 0; c < 9; ++c) A4[c] = LD(c, t4);
            const float4 e1v = LD(i1, t4), e2v = LD(i2, t4);
            const float4 f0v = LD(i30, t4), f1v = LD(i30 + 1, t4), f2v = LD(i30 + 2, t4);
            STEP4(x); STEP4(y); STEP4(z); STEP4(w);
        }
    }
#undef STEP4
#undef LD

    if (act && g == 1) {
        if (i2 == 0 && i30 == 0) sb1[i1] = s1;
        if (i30 == 0) sb2[i1][i2] = s2;
#pragma unroll
        for (int q = 0; q < 3; ++q) sb3[i1 * 9 + i2][i30 + q] = s3[q];
#pragma unroll
        for (int q = 0; q < 3; ++q)
#pragma unroll
            for (int c = 0; c < 9; ++c) sb4[base3 + q][c] = S4[q][c];
    }
    __syncthreads();

    if (act && g == 0) {
        float S1B[9];
#pragma unroll
        for (int c = 0; c < 9; ++c) S1B[c] = sb1[c];
#pragma unroll
        for (int q = 0; q < 3; ++q) {
            const float* r2 = sb2[i30 + q];
            const float* r3 = sb3[i2 * 9 + i30 + q];
            const float* r4 = sb4[base3 + q];
#pragma unroll
            for (int c = 0; c < 9; ++c)
                S4[q][c] += s3[q] * S1B[c] + s2 * r2[c] + s1 * r3[c] + r4[c];
        }
#pragma unroll
        for (int q = 0; q < 3; ++q)
            s3[q] += s2 * S1B[i30 + q] + s1 * sb2[i2][i30 + q] + sb3[i1 * 9 + i2][i30 + q];
        s2 += s1 * S1B[i2] + sb2[i1][i2];
        s1 += S1B[i1];

        float* sp = sig + (long)p * SIGCH;
        if (i2 == 0 && i30 == 0) sp[i1] = s1;
        if (i30 == 0) sp[9 + base3 / 9] = s2;
        sp[90 + base3 + 0] = s3[0];
        sp[90 + base3 + 1] = s3[1];
        sp[90 + base3 + 2] = s3[2];
#pragma unroll
        for (int q = 0; q < 3; q++)
#pragma unroll
            for (int l = 0; l < 9; l++)
                sp[819 + (base3 + q) * 9 + l] = S4[q][l];
    }
}

// ---------------- Kernel 2: GEMM1 partials (readlane-z, 2x TLP) ----------------
// 512 thr / 8 waves, 64x256 tile, grid = 2 n-halves x ksplit = 492 blocks
// (~2 blocks/CU = 4 waves/SIMD: cross-block TLP fills RL->FMA stalls and
// barrier gaps). Wave = 8 rows x 256 cols. z: ONE global dword per lane per
// BK=8 tile (lane=(k,r)); hot loop: compile-time v_readlane -> SGPR FMA src.
// w tile [8][256] LDS dbuf, lane-contiguous staging, 1 conflict-free
// ds_read_b128 per lane per k vs 32 FMA -> LDS ratio 0.6, VALU-bound.
__global__ __launch_bounds__(512) void gemm1_kernel(const float* __restrict__ zsig,
        const float* __restrict__ w0, float* __restrict__ part, int KCH) {
    __shared__ float wt[2][BKG][256];
    const int nh = blockIdx.x;            // 0/1
    const int kc = blockIdx.y;
    const int n0 = nh * 256, k0 = kc * KCH;
    const int tid = threadIdx.x;
    const int lane = tid & 63;
    const int wvid = __builtin_amdgcn_readfirstlane(tid >> 6);  // 0..7
    const int r0 = wvid * 8;
    const int c4 = lane * 4;
    const int sr = tid >> 6;              // staging row 0..7
    const int sc = (tid & 63) * 4;        // lane-contiguous columns

    const long zoff = (long)(r0 + (lane & 7)) * K1 + (lane >> 3);

#define RLF(V, L) __int_as_float(__builtin_amdgcn_readlane(__float_as_int(V), (L)))

    float4 wA, wA2;
    float zv, zv2;
    wA = *(const float4*)(w0 + (long)(k0 + sr) * N1 + n0 + sc);
    zv = zsig[zoff + k0];
    *(float4*)&wt[0][sr][sc] = wA;
    __syncthreads();

    float acc[8][4] = {};
    const int NT = KCH / BKG;
    int cur = 0;

    for (int t = 0; t < NT; ++t) {
        if (t + 1 < NT) {
            const int kn = k0 + (t + 1) * BKG;
            zv2 = zsig[zoff + kn];
            wA2 = *(const float4*)(w0 + (long)(kn + sr) * N1 + n0 + sc);
        }
#pragma unroll
        for (int k = 0; k < BKG; ++k) {
            const float4 wf = *(const float4*)&wt[cur][k][c4];
#define ROW(R) do { \
            const float sz = RLF(zv, k * 8 + (R)); \
            acc[R][0] += sz * wf.x; acc[R][1] += sz * wf.y; \
            acc[R][2] += sz * wf.z; acc[R][3] += sz * wf.w; } while (0)
            ROW(0); ROW(1); ROW(2); ROW(3); ROW(4); ROW(5); ROW(6); ROW(7);
#undef ROW
        }
        if (t + 1 < NT) {
            *(float4*)&wt[cur ^ 1][sr][sc] = wA2;
        }
        __syncthreads();
        cur ^= 1;
        zv = zv2;
    }
#undef RLF

    float* pp = part + ((long)kc * 64 + r0) * N1 + n0 + c4;
#pragma unroll
    for (int r = 0; r < 8; r++)
        *(float4*)(pp + (long)r * N1) =
            make_float4(acc[r][0], acc[r][1], acc[r][2], acc[r][3]);
}

// ---------------- Kernel 3: reduce partials + bias + sigmoid ----------------
__global__ __launch_bounds__(256) void red1_kernel(const float* __restrict__ part,
        const float* __restrict__ b0v, float* __restrict__ z1, int ksplit) {
    __shared__ float4 red[256];
    const int tid = threadIdx.x;
    const int g = tid & 31, s = tid >> 5;
    const int gg = blockIdx.x * 32 + g;
    const int per = (ksplit + 7) >> 3;
    const int ks = s * per, ke = min(ksplit, ks + per);
    float4 a = make_float4(0.f, 0.f, 0.f, 0.f);
    for (int kc = ks; kc < ke; kc++) {
        float4 pv = *(const float4*)(part + ((long)kc * 8192 + gg) * 4);
        a.x += pv.x; a.y += pv.y; a.z += pv.z; a.w += pv.w;
    }
    red[tid] = a;
    __syncthreads();
    if (tid < 128) { float4 o = red[tid + 128]; red[tid].x += o.x; red[tid].y += o.y; red[tid].z += o.z; red[tid].w += o.w; }
    __syncthreads();
    if (tid < 64) { float4 o = red[tid + 64]; red[tid].x += o.x; red[tid].y += o.y; red[tid].z += o.z; red[tid].w += o.w; }
    __syncthreads();
    if (tid < 32) {
        float4 sum = red[tid];
        float4 o = red[tid + 32];
        sum.x += o.x; sum.y += o.y; sum.z += o.z; sum.w += o.w;
        const float4 bv = *(const float4*)(b0v + (gg & 127) * 4);
        float4 r;
        r.x = 1.f / (1.f + expf(-(sum.x + bv.x)));
        r.y = 1.f / (1.f + expf(-(sum.y + bv.y)));
        r.z = 1.f / (1.f + expf(-(sum.z + bv.z)));
        r.w = 1.f / (1.f + expf(-(sum.w + bv.w)));
        *(float4*)(z1 + gg * 4) = r;
    }
}

// ---------------- Kernel 4: fused GEMM2+sigmoid+GEMM3+log_softmax ----------------
__global__ __launch_bounds__(256) void tail_kernel(const float* __restrict__ z1,
        const float* __restrict__ w1, const float* __restrict__ b1v,
        const float* __restrict__ w2, const float* __restrict__ b2v,
        float* __restrict__ out) {
    __shared__ float z2row[N2];
    __shared__ float red[160];
    __shared__ float logits[10];
    const int m = blockIdx.x;
    const int tid = threadIdx.x;
    const float* zr = z1 + m * N1;
    float acc = b1v[tid];
#pragma unroll 8
    for (int k = 0; k < N1; k++) acc += zr[k] * w1[(long)k * N2 + tid];
    z2row[tid] = 1.f / (1.f + expf(-acc));
    __syncthreads();
    if (tid < 160) {
        const int j = tid >> 4, s = tid & 15;
        float p = 0.f;
#pragma unroll
        for (int kk = 0; kk < 16; kk++) {
            const int k = s * 16 + kk;
            p += z2row[k] * w2[k * 10 + j];
        }
        red[tid] = p;
    }
    __syncthreads();
    if (tid < 10) {
        float lg = b2v[tid];
#pragma unroll
        for (int s = 0; s < 16; s++) lg += red[tid * 16 + s];
        logits[tid] = lg;
    }
    __syncthreads();
    if (tid == 0) {
        float mx = logits[0];
        for (int j = 1; j < 10; j++) mx = fmaxf(mx, logits[j]);
        float sum = 0.f;
        for (int j = 0; j < 10; j++) sum += expf(logits[j] - mx);
        const float lse = mx + logf(sum);
        for (int j = 0; j < 10; j++) out[m * 10 + j] = logits[j] - lse;
    }
}

extern "C" void kernel_launch(void* const* d_in, const int* in_sizes, int n_in,
                              void* d_out, int out_size, void* d_ws, size_t ws_size,
                              hipStream_t stream) {
    const float* x  = (const float*)d_in[0];
    const float* cw = (const float*)d_in[1];
    const float* cb = (const float*)d_in[2];
    const float* w0 = (const float*)d_in[3];
    const float* b0 = (const float*)d_in[4];
    const float* w1 = (const float*)d_in[5];
    const float* b1 = (const float*)d_in[6];
    const float* w2 = (const float*)d_in[7];
    const float* b2 = (const float*)d_in[8];

    // tiered K-split by workspace: 29520 = ksplit * KCH, KCH % 8 == 0
    const size_t fixed = (size_t)NPATH * SIGCH + 64 * N1 + 64 * N2;
    int ksplit = 82, kch = 360;
    if (ws_size >= (fixed + (size_t)246 * 64 * N1) * 4)      { ksplit = 246; kch = 120; }
    else if (ws_size >= (fixed + (size_t)123 * 64 * N1) * 4) { ksplit = 123; kch = 240; }

    float* ws   = (float*)d_ws;
    float* sigb = ws;                                // 256 x 7380 row-major
    float* part = sigb + (long)NPATH * SIGCH;        // ksplit*64*512
    float* z1   = part + (long)ksplit * 64 * N1;     // 64*512
    float* out  = (float*)d_out;

    sig_kernel<<<NPATH, 512, 0, stream>>>(x, cw, cb, sigb);
    gemm1_kernel<<<dim3(2, ksplit), 512, 0, stream>>>(sigb, w0, part, kch);
    red1_kernel<<<256, 256, 0, stream>>>(part, b0, z1, ksplit);
    tail_kernel<<<64, 256, 0, stream>>>(z1, w1, b1, w2, b2, out);
}

// Round 17
// 86.807 us; speedup vs baseline: 1.1419x; 1.1419x over previous
//
#include <hip/hip_runtime.h>
#include <hip/hip_bf16.h>
#include <math.h>

#define TT 128
#define IN_CH 32
#define NPATH 256
#define SIGCH 7380
#define K1 29520
#define N1 512
#define N2 256

typedef __attribute__((ext_vector_type(8))) short bf16x8;
typedef __attribute__((ext_vector_type(4))) float f32x4;

static __device__ __forceinline__ unsigned pack2bf(float a, float b) {
    union { __hip_bfloat162 h2; unsigned u; } cv;
    cv.h2.x = __float2bfloat16(a);
    cv.h2.y = __float2bfloat16(b);
    return cv.u;
}

// ---------------- Kernel 1: conv + time-augment + depth-4 signature ----------------
// (byte-identical structure to r16 — kept fixed for clean attribution; with
// gemm1 now ~12us this kernel will surface in the top-5 with counters)
__global__ __launch_bounds__(512, 1) void sig_kernel(const float* __restrict__ x,
        const float* __restrict__ cw, const float* __restrict__ cb,
        float* __restrict__ sig /*[256][7380]*/) {
    __shared__ float incT[9][132];
    __shared__ __align__(16) float sb1[12];
    __shared__ __align__(16) float sb2[9][12];
    __shared__ __align__(16) float sb3[81][12];
    __shared__ __align__(16) float sb4[729][12];
    const int p = blockIdx.x;
    const int b = p >> 2, oc = p & 3;
    const int tid = threadIdx.x;

    const float4 wv = *(const float4*)(cw + oc * 4);
    const float bias = cb[oc];
    const float* xb = x + (long)b * TT * IN_CH;

    for (int it = tid; it < TT * 8; it += 512) {
        const int t = it >> 3, ch = it & 7;
        const float4 xa = *(const float4*)(xb + t * IN_CH + ch * 4);
        float v = xa.x * wv.x + xa.y * wv.y + xa.z * wv.z + xa.w * wv.w + bias;
        if (t > 0) {
            const float4 xm = *(const float4*)(xb + (t - 1) * IN_CH + ch * 4);
            v -= xm.x * wv.x + xm.y * wv.y + xm.z * wv.z + xm.w * wv.w + bias;
        }
        incT[1 + ch][t] = v;
    }
    if (tid < TT) incT[0][tid] = tid ? (1.f / 127.f) : 0.f;
    __syncthreads();

    const int g = tid >> 8;
    const int gtid = tid & 255;
    const bool act = gtid < 243;
    const int base3 = 3 * gtid;
    const int i1 = base3 / 81;
    const int i2 = (base3 / 9) % 9;
    const int i30 = base3 % 9;

    float S4[3][9] = {};
    float s3[3] = {0.f, 0.f, 0.f};
    float s2 = 0.f, s1 = 0.f;

#define LD(R, T4) (*(const float4*)&incT[(R)][(T4)])
#define STEP4(CMP) do { \
    const float E1 = e1v.CMP, E2 = e2v.CMP; \
    const float F0 = f0v.CMP, F1 = f1v.CMP, F2 = f2v.CMP; \
    const float t12 = E1 * E2; \
    const float s1d2 = s1 * E2; \
    const float Ak = t12 * (1.f / 24.f) + s1d2 * (1.f / 6.f) + s2 * 0.5f; \
    const float Bk = t12 * (1.f / 6.f) + s1d2 * 0.5f + s2; \
    const float K0 = F0 * Ak + s3[0]; \
    const float K1v = F1 * Ak + s3[1]; \
    const float K2v = F2 * Ak + s3[2]; \
    _Pragma("unroll") \
    for (int c = 0; c < 9; ++c) { \
        const float Ac = A4[c].CMP; \
        S4[0][c] += K0 * Ac; S4[1][c] += K1v * Ac; S4[2][c] += K2v * Ac; \
    } \
    s3[0] += Bk * F0; s3[1] += Bk * F1; s3[2] += Bk * F2; \
    s2 += E2 * (0.5f * E1 + s1); \
    s1 += E1; \
} while (0)

    if (act) {
        const int t0g = g * 64;
        for (int gg = 0; gg < 16; ++gg) {
            const int t4 = t0g + gg * 4;
            float4 A4[9];
#pragma unroll
            for (int c = 0; c < 9; ++c) A4[c] = LD(c, t4);
            const float4 e1v = LD(i1, t4), e2v = LD(i2, t4);
            const float4 f0v = LD(i30, t4), f1v = LD(i30 + 1, t4), f2v = LD(i30 + 2, t4);
            STEP4(x); STEP4(y); STEP4(z); STEP4(w);
        }
    }
#undef STEP4
#undef LD

    if (act && g == 1) {
        if (i2 == 0 && i30 == 0) sb1[i1] = s1;
        if (i30 == 0) sb2[i1][i2] = s2;
#pragma unroll
        for (int q = 0; q < 3; ++q) sb3[i1 * 9 + i2][i30 + q] = s3[q];
#pragma unroll
        for (int q = 0; q < 3; ++q)
#pragma unroll
            for (int c = 0; c < 9; ++c) sb4[base3 + q][c] = S4[q][c];
    }
    __syncthreads();

    if (act && g == 0) {
        float S1B[9];
#pragma unroll
        for (int c = 0; c < 9; ++c) S1B[c] = sb1[c];
#pragma unroll
        for (int q = 0; q < 3; ++q) {
            const float* r2 = sb2[i30 + q];
            const float* r3 = sb3[i2 * 9 + i30 + q];
            const float* r4 = sb4[base3 + q];
#pragma unroll
            for (int c = 0; c < 9; ++c)
                S4[q][c] += s3[q] * S1B[c] + s2 * r2[c] + s1 * r3[c] + r4[c];
        }
#pragma unroll
        for (int q = 0; q < 3; ++q)
            s3[q] += s2 * S1B[i30 + q] + s1 * sb2[i2][i30 + q] + sb3[i1 * 9 + i2][i30 + q];
        s2 += s1 * S1B[i2] + sb2[i1][i2];
        s1 += S1B[i1];

        float* sp = sig + (long)p * SIGCH;
        if (i2 == 0 && i30 == 0) sp[i1] = s1;
        if (i30 == 0) sp[9 + base3 / 9] = s2;
        sp[90 + base3 + 0] = s3[0];
        sp[90 + base3 + 1] = s3[1];
        sp[90 + base3 + 2] = s3[2];
#pragma unroll
        for (int q = 0; q < 3; q++)
#pragma unroll
            for (int l = 0; l < 9; l++)
                sp[819 + (base3 + q) * 9 + l] = S4[q][l];
    }
}

// ---------------- Kernel 2: GEMM1 partials via bf16 MFMA ----------------
// Grid = 4 n-quarters x ksplit; block = 64 rows x 128 cols x (nsub*120) k,
// 256 thr / 4 waves. Per 120-k sub-chunk: stage z and w0 (f32->bf16 cvt on
// the fly) into LDS (za[64][136], wb[128][136] bf16, k zero-padded to 128),
// then 4 ksteps x 8 col-tiles of mfma_f32_16x16x32_bf16 per wave.
// D-mapping (m89-verified): col=lane&15, row=(lane>>4)*4+j.
__global__ __launch_bounds__(256) void gemm1_kernel(const float* __restrict__ zsig,
        const float* __restrict__ w0, float* __restrict__ part, int nsub) {
    __shared__ unsigned short za[64][136];
    __shared__ unsigned short wb[128][136];
    const int nq = blockIdx.x;            // 0..3
    const int kc = blockIdx.y;
    const int n0 = nq * 128;
    const int k0 = kc * nsub * 120;
    const int tid = threadIdx.x;
    const int lane = tid & 63;
    const int wvid = __builtin_amdgcn_readfirstlane(tid >> 6);  // 0..3
    const int r0 = wvid * 16;
    const int rA = lane & 15, gr = lane >> 4;

    // zero the k-pad [120,128) once (never overwritten by staging)
    *(unsigned*)&za[tid >> 2][120 + 2 * (tid & 3)] = 0u;
    for (int i = tid; i < 512; i += 256)
        *(unsigned*)&wb[i >> 2][120 + 2 * (i & 3)] = 0u;

    f32x4 acc[8];
#pragma unroll
    for (int t = 0; t < 8; ++t) acc[t] = (f32x4){0.f, 0.f, 0.f, 0.f};

    for (int s = 0; s < nsub; ++s) {
        const int kb = k0 + s * 120;
        if (s) __syncthreads();           // previous MFMA reads done
        // stage z: 64 rows x 60 k-pairs
        for (int i = tid; i < 64 * 60; i += 256) {
            const int row = i / 60, kp = i % 60;
            const float2 v = *(const float2*)(zsig + (long)row * K1 + kb + 2 * kp);
            *(unsigned*)&za[row][2 * kp] = pack2bf(v.x, v.y);
        }
        // stage w: 128 cols x 60 k-pairs (transposed, cvt to bf16)
        for (int i = tid; i < 128 * 60; i += 256) {
            const int c = i & 127, kp = i >> 7;
            const float a = w0[(long)(kb + 2 * kp) * N1 + n0 + c];
            const float bvl = w0[(long)(kb + 2 * kp + 1) * N1 + n0 + c];
            *(unsigned*)&wb[c][2 * kp] = pack2bf(a, bvl);
        }
        __syncthreads();
        // MFMA: 4 ksteps x 8 col-tiles
#pragma unroll
        for (int ks = 0; ks < 4; ++ks) {
            const bf16x8 af = *(const bf16x8*)&za[r0 + rA][ks * 32 + gr * 8];
#pragma unroll
            for (int t = 0; t < 8; ++t) {
                const bf16x8 bf = *(const bf16x8*)&wb[rA + 16 * t][ks * 32 + gr * 8];
                acc[t] = __builtin_amdgcn_mfma_f32_16x16x32_bf16(af, bf, acc[t], 0, 0, 0);
            }
        }
    }

    // write partial tile: part[kc][64][512]; D: row=(gr*4+j), col=rA (+16t)
    float* pp = part + ((long)kc * 64 + r0 + 4 * gr) * N1 + n0 + rA;
#pragma unroll
    for (int t = 0; t < 8; ++t)
#pragma unroll
        for (int j = 0; j < 4; ++j)
            pp[(long)j * N1 + 16 * t] = acc[t][j];
}

// ---------------- Kernel 3: reduce partials + bias + sigmoid ----------------
__global__ __launch_bounds__(256) void red1_kernel(const float* __restrict__ part,
        const float* __restrict__ b0v, float* __restrict__ z1, int ksplit) {
    __shared__ float4 red[256];
    const int tid = threadIdx.x;
    const int g = tid & 31, s = tid >> 5;
    const int gg = blockIdx.x * 32 + g;
    const int per = (ksplit + 7) >> 3;
    const int ks = s * per, ke = min(ksplit, ks + per);
    float4 a = make_float4(0.f, 0.f, 0.f, 0.f);
    for (int kc = ks; kc < ke; kc++) {
        float4 pv = *(const float4*)(part + ((long)kc * 8192 + gg) * 4);
        a.x += pv.x; a.y += pv.y; a.z += pv.z; a.w += pv.w;
    }
    red[tid] = a;
    __syncthreads();
    if (tid < 128) { float4 o = red[tid + 128]; red[tid].x += o.x; red[tid].y += o.y; red[tid].z += o.z; red[tid].w += o.w; }
    __syncthreads();
    if (tid < 64) { float4 o = red[tid + 64]; red[tid].x += o.x; red[tid].y += o.y; red[tid].z += o.z; red[tid].w += o.w; }
    __syncthreads();
    if (tid < 32) {
        float4 sum = red[tid];
        float4 o = red[tid + 32];
        sum.x += o.x; sum.y += o.y; sum.z += o.z; sum.w += o.w;
        const float4 bv = *(const float4*)(b0v + (gg & 127) * 4);
        float4 r;
        r.x = 1.f / (1.f + expf(-(sum.x + bv.x)));
        r.y = 1.f / (1.f + expf(-(sum.y + bv.y)));
        r.z = 1.f / (1.f + expf(-(sum.z + bv.z)));
        r.w = 1.f / (1.f + expf(-(sum.w + bv.w)));
        *(float4*)(z1 + gg * 4) = r;
    }
}

// ---------------- Kernel 4: fused GEMM2+sigmoid+GEMM3+log_softmax ----------------
__global__ __launch_bounds__(256) void tail_kernel(const float* __restrict__ z1,
        const float* __restrict__ w1, const float* __restrict__ b1v,
        const float* __restrict__ w2, const float* __restrict__ b2v,
        float* __restrict__ out) {
    __shared__ float z2row[N2];
    __shared__ float red[160];
    __shared__ float logits[10];
    const int m = blockIdx.x;
    const int tid = threadIdx.x;
    const float* zr = z1 + m * N1;
    float acc = b1v[tid];
#pragma unroll 8
    for (int k = 0; k < N1; k++) acc += zr[k] * w1[(long)k * N2 + tid];
    z2row[tid] = 1.f / (1.f + expf(-acc));
    __syncthreads();
    if (tid < 160) {
        const int j = tid >> 4, s = tid & 15;
        float p = 0.f;
#pragma unroll
        for (int kk = 0; kk < 16; kk++) {
            const int k = s * 16 + kk;
            p += z2row[k] * w2[k * 10 + j];
        }
        red[tid] = p;
    }
    __syncthreads();
    if (tid < 10) {
        float lg = b2v[tid];
#pragma unroll
        for (int s = 0; s < 16; s++) lg += red[tid * 16 + s];
        logits[tid] = lg;
    }
    __syncthreads();
    if (tid == 0) {
        float mx = logits[0];
        for (int j = 1; j < 10; j++) mx = fmaxf(mx, logits[j]);
        float sum = 0.f;
        for (int j = 0; j < 10; j++) sum += expf(logits[j] - mx);
        const float lse = mx + logf(sum);
        for (int j = 0; j < 10; j++) out[m * 10 + j] = logits[j] - lse;
    }
}

extern "C" void kernel_launch(void* const* d_in, const int* in_sizes, int n_in,
                              void* d_out, int out_size, void* d_ws, size_t ws_size,
                              hipStream_t stream) {
    const float* x  = (const float*)d_in[0];
    const float* cw = (const float*)d_in[1];
    const float* cb = (const float*)d_in[2];
    const float* w0 = (const float*)d_in[3];
    const float* b0 = (const float*)d_in[4];
    const float* w1 = (const float*)d_in[5];
    const float* b1 = (const float*)d_in[6];
    const float* w2 = (const float*)d_in[7];
    const float* b2 = (const float*)d_in[8];

    // tiered K-split: ksplit * nsub * 120 = 29520
    const size_t fixed = (size_t)NPATH * SIGCH + 64 * N1 + 64 * N2;
    int ksplit = 82, nsub = 3;
    if (ws_size >= (fixed + (size_t)246 * 64 * N1) * 4)      { ksplit = 246; nsub = 1; }
    else if (ws_size >= (fixed + (size_t)123 * 64 * N1) * 4) { ksplit = 123; nsub = 2; }

    float* ws   = (float*)d_ws;
    float* sigb = ws;                                // 256 x 7380 row-major
    float* part = sigb + (long)NPATH * SIGCH;        // ksplit*64*512
    float* z1   = part + (long)ksplit * 64 * N1;     // 64*512
    float* out  = (float*)d_out;

    sig_kernel<<<NPATH, 512, 0, stream>>>(x, cw, cb, sigb);
    gemm1_kernel<<<dim3(4, ksplit), 256, 0, stream>>>(sigb, w0, part, nsub);
    red1_kernel<<<256, 256, 0, stream>>>(part, b0, z1, ksplit);
    tail_kernel<<<64, 256, 0, stream>>>(z1, w1, b1, w2, b2, out);
}

// Round 18
// 68.832 us; speedup vs baseline: 1.4400x; 1.2611x over previous
//
#include <hip/hip_runtime.h>
#include <hip/hip_bf16.h>
#include <math.h>

#define TT 128
#define IN_CH 32
#define NPATH 256
#define SIGCH 7380
#define K1 29520
#define N1 512
#define N2 256

typedef __attribute__((ext_vector_type(8))) short bf16x8;
typedef __attribute__((ext_vector_type(4))) float f32x4;

static __device__ __forceinline__ unsigned pack2bf(float a, float b) {
    union { __hip_bfloat162 h2; unsigned u; } cv;
    cv.h2.x = __float2bfloat16(a);
    cv.h2.y = __float2bfloat16(b);
    return cv.u;
}

// ---------------- Kernel 1: conv + time-augment + depth-4 signature ----------------
// (byte-identical to r16/r17 — will now surface in top-5 with counters)
__global__ __launch_bounds__(512, 1) void sig_kernel(const float* __restrict__ x,
        const float* __restrict__ cw, const float* __restrict__ cb,
        float* __restrict__ sig /*[256][7380]*/) {
    __shared__ float incT[9][132];
    __shared__ __align__(16) float sb1[12];
    __shared__ __align__(16) float sb2[9][12];
    __shared__ __align__(16) float sb3[81][12];
    __shared__ __align__(16) float sb4[729][12];
    const int p = blockIdx.x;
    const int b = p >> 2, oc = p & 3;
    const int tid = threadIdx.x;

    const float4 wv = *(const float4*)(cw + oc * 4);
    const float bias = cb[oc];
    const float* xb = x + (long)b * TT * IN_CH;

    for (int it = tid; it < TT * 8; it += 512) {
        const int t = it >> 3, ch = it & 7;
        const float4 xa = *(const float4*)(xb + t * IN_CH + ch * 4);
        float v = xa.x * wv.x + xa.y * wv.y + xa.z * wv.z + xa.w * wv.w + bias;
        if (t > 0) {
            const float4 xm = *(const float4*)(xb + (t - 1) * IN_CH + ch * 4);
            v -= xm.x * wv.x + xm.y * wv.y + xm.z * wv.z + xm.w * wv.w + bias;
        }
        incT[1 + ch][t] = v;
    }
    if (tid < TT) incT[0][tid] = tid ? (1.f / 127.f) : 0.f;
    __syncthreads();

    const int g = tid >> 8;
    const int gtid = tid & 255;
    const bool act = gtid < 243;
    const int base3 = 3 * gtid;
    const int i1 = base3 / 81;
    const int i2 = (base3 / 9) % 9;
    const int i30 = base3 % 9;

    float S4[3][9] = {};
    float s3[3] = {0.f, 0.f, 0.f};
    float s2 = 0.f, s1 = 0.f;

#define LD(R, T4) (*(const float4*)&incT[(R)][(T4)])
#define STEP4(CMP) do { \
    const float E1 = e1v.CMP, E2 = e2v.CMP; \
    const float F0 = f0v.CMP, F1 = f1v.CMP, F2 = f2v.CMP; \
    const float t12 = E1 * E2; \
    const float s1d2 = s1 * E2; \
    const float Ak = t12 * (1.f / 24.f) + s1d2 * (1.f / 6.f) + s2 * 0.5f; \
    const float Bk = t12 * (1.f / 6.f) + s1d2 * 0.5f + s2; \
    const float K0 = F0 * Ak + s3[0]; \
    const float K1v = F1 * Ak + s3[1]; \
    const float K2v = F2 * Ak + s3[2]; \
    _Pragma("unroll") \
    for (int c = 0; c < 9; ++c) { \
        const float Ac = A4[c].CMP; \
        S4[0][c] += K0 * Ac; S4[1][c] += K1v * Ac; S4[2][c] += K2v * Ac; \
    } \
    s3[0] += Bk * F0; s3[1] += Bk * F1; s3[2] += Bk * F2; \
    s2 += E2 * (0.5f * E1 + s1); \
    s1 += E1; \
} while (0)

    if (act) {
        const int t0g = g * 64;
        for (int gg = 0; gg < 16; ++gg) {
            const int t4 = t0g + gg * 4;
            float4 A4[9];
#pragma unroll
            for (int c = 0; c < 9; ++c) A4[c] = LD(c, t4);
            const float4 e1v = LD(i1, t4), e2v = LD(i2, t4);
            const float4 f0v = LD(i30, t4), f1v = LD(i30 + 1, t4), f2v = LD(i30 + 2, t4);
            STEP4(x); STEP4(y); STEP4(z); STEP4(w);
        }
    }
#undef STEP4
#undef LD

    if (act && g == 1) {
        if (i2 == 0 && i30 == 0) sb1[i1] = s1;
        if (i30 == 0) sb2[i1][i2] = s2;
#pragma unroll
        for (int q = 0; q < 3; ++q) sb3[i1 * 9 + i2][i30 + q] = s3[q];
#pragma unroll
        for (int q = 0; q < 3; ++q)
#pragma unroll
            for (int c = 0; c < 9; ++c) sb4[base3 + q][c] = S4[q][c];
    }
    __syncthreads();

    if (act && g == 0) {
        float S1B[9];
#pragma unroll
        for (int c = 0; c < 9; ++c) S1B[c] = sb1[c];
#pragma unroll
        for (int q = 0; q < 3; ++q) {
            const float* r2 = sb2[i30 + q];
            const float* r3 = sb3[i2 * 9 + i30 + q];
            const float* r4 = sb4[base3 + q];
#pragma unroll
            for (int c = 0; c < 9; ++c)
                S4[q][c] += s3[q] * S1B[c] + s2 * r2[c] + s1 * r3[c] + r4[c];
        }
#pragma unroll
        for (int q = 0; q < 3; ++q)
            s3[q] += s2 * S1B[i30 + q] + s1 * sb2[i2][i30 + q] + sb3[i1 * 9 + i2][i30 + q];
        s2 += s1 * S1B[i2] + sb2[i1][i2];
        s1 += S1B[i1];

        float* sp = sig + (long)p * SIGCH;
        if (i2 == 0 && i30 == 0) sp[i1] = s1;
        if (i30 == 0) sp[9 + base3 / 9] = s2;
        sp[90 + base3 + 0] = s3[0];
        sp[90 + base3 + 1] = s3[1];
        sp[90 + base3 + 2] = s3[2];
#pragma unroll
        for (int q = 0; q < 3; q++)
#pragma unroll
            for (int l = 0; l < 9; l++)
                sp[819 + (base3 + q) * 9 + l] = S4[q][l];
    }
}

// ---------------- Kernel 2: GEMM1 partials via bf16 MFMA (occupancy-tuned) ----------------
// 64x64 tile (za+wb = 35KB LDS -> 4 blocks/CU = 16 waves/CU for HBM streaming).
// Grid = 8 col-groups x ksplit k-chunks; nsub sub-chunks of K=120 (padded 128).
// Stage z,w0 f32->bf16 into LDS, 4 ks x 4 col-tiles mfma_f32_16x16x32_bf16/wave.
__global__ __launch_bounds__(256) void gemm1_kernel(const float* __restrict__ zsig,
        const float* __restrict__ w0, float* __restrict__ part, int nsub) {
    __shared__ unsigned short za[64][136];
    __shared__ unsigned short wb[64][136];
    const int nq = blockIdx.x;            // 0..7
    const int kc = blockIdx.y;
    const int n0 = nq * 64;
    const int tid = threadIdx.x;
    const int lane = tid & 63;
    const int wvid = __builtin_amdgcn_readfirstlane(tid >> 6);  // 0..3
    const int r0 = wvid * 16;
    const int rA = lane & 15, gr = lane >> 4;

    // zero k-pad [120,128) once (one dword per thread covers 64 rows x 4 dwords)
    {
        const int row = tid >> 2, off = 120 + 2 * (tid & 3);
        *(unsigned*)&za[row][off] = 0u;
        *(unsigned*)&wb[row][off] = 0u;
    }

    f32x4 acc[4];
#pragma unroll
    for (int t = 0; t < 4; ++t) acc[t] = (f32x4){0.f, 0.f, 0.f, 0.f};

    for (int s = 0; s < nsub; ++s) {
        const int kb = (blockIdx.y * nsub + s) * 120;
        if (s) __syncthreads();
        // stage z: 64 rows x 60 k-pairs (16 iters/thread, kp<60 guard)
#pragma unroll
        for (int j = 0; j < 16; ++j) {
            const int i = tid + j * 256;
            const int row = i >> 6, kp = i & 63;
            if (kp < 60) {
                const float2 v = *(const float2*)(zsig + (long)row * K1 + kb + 2 * kp);
                *(unsigned*)&za[row][2 * kp] = pack2bf(v.x, v.y);
            }
        }
        // stage w: 64 cols x 60 k-pairs (transposed, coalesced reads)
#pragma unroll
        for (int j = 0; j < 16; ++j) {
            const int i = tid + j * 256;
            const int c = i & 63, kq = i >> 6;
            if (kq < 60) {
                const float a = w0[(long)(kb + 2 * kq) * N1 + n0 + c];
                const float bvl = w0[(long)(kb + 2 * kq + 1) * N1 + n0 + c];
                *(unsigned*)&wb[c][2 * kq] = pack2bf(a, bvl);
            }
        }
        __syncthreads();
#pragma unroll
        for (int ks = 0; ks < 4; ++ks) {
            const bf16x8 af = *(const bf16x8*)&za[r0 + rA][ks * 32 + gr * 8];
#pragma unroll
            for (int t = 0; t < 4; ++t) {
                const bf16x8 bf = *(const bf16x8*)&wb[16 * t + rA][ks * 32 + gr * 8];
                acc[t] = __builtin_amdgcn_mfma_f32_16x16x32_bf16(af, bf, acc[t], 0, 0, 0);
            }
        }
    }

    // D: row = r0 + 4*gr + j, col = n0 + 16*t + rA
    float* pp = part + ((long)blockIdx.y * 64 + r0 + 4 * gr) * N1 + n0 + rA;
#pragma unroll
    for (int t = 0; t < 4; ++t)
#pragma unroll
        for (int j = 0; j < 4; ++j)
            pp[(long)j * N1 + 16 * t] = acc[t][j];
}

// ---------------- Kernel 3: reduce partials + bias + sigmoid ----------------
// 512 blocks x 256 thr; block owns 16 float4 cells, 16 k-slices in-block.
__global__ __launch_bounds__(256) void red1_kernel(const float* __restrict__ part,
        const float* __restrict__ b0v, float* __restrict__ z1, int ksplit) {
    __shared__ float4 red[256];
    const int tid = threadIdx.x;
    const int cellL = tid & 15, slice = tid >> 4;
    const int cell = blockIdx.x * 16 + cellL;      // float4 index in [0, 8192)
    const int per = (ksplit + 15) >> 4;
    const int ks = slice * per, ke = min(ksplit, ks + per);
    float4 a = make_float4(0.f, 0.f, 0.f, 0.f);
    for (int kc = ks; kc < ke; kc++) {
        const float4 pv = *(const float4*)(part + ((long)kc * 8192 + cell) * 4);
        a.x += pv.x; a.y += pv.y; a.z += pv.z; a.w += pv.w;
    }
    red[tid] = a;
    __syncthreads();
    if (tid < 128) { float4 o = red[tid + 128]; red[tid].x += o.x; red[tid].y += o.y; red[tid].z += o.z; red[tid].w += o.w; }
    __syncthreads();
    if (tid < 64) { float4 o = red[tid + 64]; red[tid].x += o.x; red[tid].y += o.y; red[tid].z += o.z; red[tid].w += o.w; }
    __syncthreads();
    if (tid < 32) { float4 o = red[tid + 32]; red[tid].x += o.x; red[tid].y += o.y; red[tid].z += o.z; red[tid].w += o.w; }
    __syncthreads();
    if (tid < 16) {
        float4 sum = red[tid];
        float4 o = red[tid + 16];
        sum.x += o.x; sum.y += o.y; sum.z += o.z; sum.w += o.w;
        const float4 bv = *(const float4*)(b0v + (cell & 127) * 4);
        float4 r;
        r.x = 1.f / (1.f + expf(-(sum.x + bv.x)));
        r.y = 1.f / (1.f + expf(-(sum.y + bv.y)));
        r.z = 1.f / (1.f + expf(-(sum.z + bv.z)));
        r.w = 1.f / (1.f + expf(-(sum.w + bv.w)));
        *(float4*)(z1 + cell * 4) = r;
    }
}

// ---------------- Kernel 4: GEMM2 + bias + sigmoid (in-block K-split) ----------------
__global__ __launch_bounds__(256) void gemm2_kernel(const float* __restrict__ z1,
        const float* __restrict__ w1, const float* __restrict__ b1v,
        float* __restrict__ z2) {
    __shared__ float red[256];
    const int m = blockIdx.x >> 2, nq = blockIdx.x & 3;
    const int tid = threadIdx.x;
    const int c = tid & 63, s = tid >> 6;
    const int n = nq * 64 + c;
    const float* zr = z1 + m * N1 + s * 128;
    const float* wr = w1 + (long)(s * 128) * N2 + n;
    float acc = 0.f;
#pragma unroll 16
    for (int k = 0; k < 128; k++) acc += zr[k] * wr[(long)k * N2];
    red[tid] = acc;
    __syncthreads();
    if (tid < 128) red[tid] += red[tid + 128];
    __syncthreads();
    if (tid < 64) {
        float sum = red[tid] + red[tid + 64] + b1v[n];
        z2[m * N2 + n] = 1.f / (1.f + expf(-sum));
    }
}

// ---------------- Kernel 5: GEMM3 + log_softmax ----------------
__global__ __launch_bounds__(64) void head_kernel(const float* __restrict__ z2,
        const float* __restrict__ w2, const float* __restrict__ b2v,
        float* __restrict__ out) {
    const int m = blockIdx.x;
    const int tid = threadIdx.x;
    __shared__ float logits[10];
    if (tid < 10) {
        float s = b2v[tid];
        const float* zr = z2 + m * N2;
#pragma unroll 8
        for (int k = 0; k < N2; k++) s += zr[k] * w2[k * 10 + tid];
        logits[tid] = s;
    }
    __syncthreads();
    if (tid == 0) {
        float mx = logits[0];
        for (int j = 1; j < 10; j++) mx = fmaxf(mx, logits[j]);
        float sum = 0.f;
        for (int j = 0; j < 10; j++) sum += expf(logits[j] - mx);
        const float lse = mx + logf(sum);
        for (int j = 0; j < 10; j++) out[m * 10 + j] = logits[j] - lse;
    }
}

extern "C" void kernel_launch(void* const* d_in, const int* in_sizes, int n_in,
                              void* d_out, int out_size, void* d_ws, size_t ws_size,
                              hipStream_t stream) {
    const float* x  = (const float*)d_in[0];
    const float* cw = (const float*)d_in[1];
    const float* cb = (const float*)d_in[2];
    const float* w0 = (const float*)d_in[3];
    const float* b0 = (const float*)d_in[4];
    const float* w1 = (const float*)d_in[5];
    const float* b1 = (const float*)d_in[6];
    const float* w2 = (const float*)d_in[7];
    const float* b2 = (const float*)d_in[8];

    // tiered K-split: ksplit * nsub * 120 = 29520
    const size_t fixed = (size_t)NPATH * SIGCH + 64 * N1 + 64 * N2;
    int ksplit = 41, nsub = 6;
    if (ws_size >= (fixed + (size_t)123 * 64 * N1) * 4)      { ksplit = 123; nsub = 2; }
    else if (ws_size >= (fixed + (size_t)82 * 64 * N1) * 4)  { ksplit = 82;  nsub = 3; }

    float* ws   = (float*)d_ws;
    float* sigb = ws;                                // 256 x 7380 row-major
    float* part = sigb + (long)NPATH * SIGCH;        // ksplit*64*512
    float* z1   = part + (long)ksplit * 64 * N1;     // 64*512
    float* z2   = z1 + 64 * N1;                      // 64*256
    float* out  = (float*)d_out;

    sig_kernel<<<NPATH, 512, 0, stream>>>(x, cw, cb, sigb);
    gemm1_kernel<<<dim3(8, ksplit), 256, 0, stream>>>(sigb, w0, part, nsub);
    red1_kernel<<<512, 256, 0, stream>>>(part, b0, z1, ksplit);
    gemm2_kernel<<<256, 256, 0, stream>>>(z1, w1, b1, z2);
    head_kernel<<<64, 64, 0, stream>>>(z2, w2, b2, out);
}